// Round 5
// baseline (696.467 us; speedup 1.0000x reference)
//
#include <hip/hip_runtime.h>
#include <math.h>

// Problem constants (match reference):
#define BB    2
#define NN    8192
#define DD    256
#define NBINS 32
#define BINSZ 256
#define NPROJ 16     // n_bins // 2
#define TOPK  16
#define NPTS  (BB * NN)   // 16384

typedef float vf4 __attribute__((ext_vector_type(4)));  // native vec for nt-store

// ---------------------------------------------------------------------------
// K1: bin assignment. Codebook staged as fp64 in LDS (cvt once; FMA order
// unchanged vs rounds 1-4 -> still bit-identical to the numpy reference).
// ---------------------------------------------------------------------------
__global__ __launch_bounds__(64) void k_bins(const float* __restrict__ x,
                                             const float* __restrict__ cb,
                                             int* __restrict__ bin_idx) {
    __shared__ double cbd[DD][NPROJ];   // 32 KB
    const int t = threadIdx.x;          // 0..63
    for (int q = t; q < DD * 4; q += 64) {
        int d = q >> 2, j4 = q & 3;
        float4 v = *(const float4*)(cb + d * 32 + j4 * 4);
        cbd[d][j4 * 4 + 0] = (double)v.x;
        cbd[d][j4 * 4 + 1] = (double)v.y;
        cbd[d][j4 * 4 + 2] = (double)v.z;
        cbd[d][j4 * 4 + 3] = (double)v.w;
    }
    __syncthreads();

    const int p = blockIdx.x * 64 + t;            // 0..16383 (flat over B,N)
    const float* xr = x + (size_t)p * DD;

    double a[NPROJ];
#pragma unroll
    for (int j = 0; j < NPROJ; ++j) a[j] = 0.0;

    for (int d0 = 0; d0 < DD; d0 += 4) {
        float4 xv = *(const float4*)(xr + d0);
        float xs[4] = {xv.x, xv.y, xv.z, xv.w};
#pragma unroll
        for (int dd = 0; dd < 4; ++dd) {
            double xd = (double)xs[dd];
#pragma unroll
            for (int j = 0; j < NPROJ; ++j)
                a[j] = fma(cbd[d0 + dd][j], xd, a[j]);
        }
    }

    float bv = -INFINITY; int bj = 0;
#pragma unroll
    for (int j = 0; j < NPROJ; ++j) {
        float m = (float)a[j];
        if (m > bv) { bv = m; bj = j; }
    }
#pragma unroll
    for (int j = 0; j < NPROJ; ++j) {
        float m = -(float)a[j];
        if (m > bv) { bv = m; bj = j + NPROJ; }
    }
    bin_idx[p] = bj;
}

// ---------------------------------------------------------------------------
// K2: stable counting sort (unchanged — ~5 us).
// ---------------------------------------------------------------------------
__global__ __launch_bounds__(256) void k_sort(const int* __restrict__ bin_idx,
                                              int* __restrict__ order) {
    __shared__ int c[NBINS][256];   // 32 KB
    __shared__ int base[NBINS];
    const int t = threadIdx.x;
    const int b = blockIdx.x;
    const int* bi = bin_idx + b * NN;

    for (int j = 0; j < NBINS; ++j) c[j][t] = 0;
    __syncthreads();

    const int i0 = t * 32;
    for (int i = 0; i < 32; ++i) c[bi[i0 + i]][t]++;
    __syncthreads();

    if (t < NBINS) {
        int s = 0;
        for (int q = 0; q < 256; ++q) s += c[t][q];
        base[t] = s;
    }
    __syncthreads();
    if (t == 0) {
        int run = 0;
        for (int j = 0; j < NBINS; ++j) { int tmp = base[j]; base[j] = run; run += tmp; }
    }
    __syncthreads();
    if (t < NBINS) {
        int run = base[t];
        for (int q = 0; q < 256; ++q) { int tmp = c[t][q]; c[t][q] = run; run += tmp; }
    }
    __syncthreads();

    int* ob = order + b * NN;
    for (int i = 0; i < 32; ++i) {
        int gi = i0 + i;
        int bb = bi[gi];
        int pos = c[bb][t]++;
        ob[pos] = gi;
    }
}

// ---------------------------------------------------------------------------
// K3 v3: single shared tile Bt[256][36] per 32-dim chunk serves BOTH operands
// (A rows r0..r0+31 are bin rows too). Cooperative coalesced staging
// (8 threads/row -> 16 lines/instr). Thread tile 8 rows x 4 cols:
// A-reads are wave-uniform LDS broadcasts, B-reads 4 b128 with even banks.
// fp64 FMA order (iter->dd4->elem ascending) == reference: absmax 0.0.
// Zero-fill of the block's 32 output rows interleaved (nt stores).
// grid = 512 blocks -> 2 blocks/CU; LDS ~73 KB -> fits 2/CU (160 KB).
// ---------------------------------------------------------------------------
#define RT 32
__global__ __launch_bounds__(256, 2) void k_sim(const float* __restrict__ x,
                                                const int* __restrict__ order,
                                                float* __restrict__ out) {
    __shared__ int   idx[BINSZ];            // 1 KB
    __shared__ float Bt[BINSZ][36];         // 36 KB (36: 16B-aligned + even banks)
    __shared__ float S[RT][BINSZ + 1];      // ~32.9 KB
    __shared__ float tvs[RT][TOPK];         // 2 KB
    __shared__ int   tds[RT][TOPK];         // 2 KB

    const int t   = threadIdx.x;
    const int bid = blockIdx.x;              // 0..511
    const int b   = bid >> 8;
    const int bin = (bid >> 3) & 31;
    const int r0  = (bid & 7) * RT;

    idx[t] = order[b * NN + bin * BINSZ + t];
    __syncthreads();

    const float* xb = x + (size_t)b * NN * DD;

    // staging assignment: thread stages chunk (t&7) of rows (t>>3)+32q, q=0..7
    const int sr_ = t >> 3, sc = t & 7;
    const float* srow[8];
#pragma unroll
    for (int q = 0; q < 8; ++q)
        srow[q] = xb + (size_t)idx[sr_ + 32 * q] * DD + sc * 4;

    // compute assignment: rows rg*8..rg*8+7 (block-local), cols (t&63)+64k
    const int rg    = t >> 6;                // == wave id -> A reads wave-uniform
    const int cbase = t & 63;

    double acc[8][4];
#pragma unroll
    for (int r = 0; r < 8; ++r)
#pragma unroll
        for (int k = 0; k < 4; ++k) acc[r][k] = 0.0;

    const vf4 z4 = (vf4)0.0f;

#pragma unroll 1
    for (int it = 0; it < 8; ++it) {
        const int k0 = it * 32;

        // global loads first (in flight while other waves drain into barrier)
        float4 st[8];
#pragma unroll
        for (int q = 0; q < 8; ++q) st[q] = *(const float4*)(srow[q] + k0);

        // zero 4 of this block's 32 output rows (fire-and-forget, nt)
        {
            const int zr = it * 4;
#pragma unroll
            for (int rr = 0; rr < 4; ++rr) {
                vf4* orow = (vf4*)(out + ((size_t)b * NN + idx[r0 + zr + rr]) * NN);
#pragma unroll
                for (int j = 0; j < 8; ++j)
                    __builtin_nontemporal_store(z4, orow + j * 256 + t);
            }
        }

        __syncthreads();   // all waves done READING Bt for iter it-1
#pragma unroll
        for (int q = 0; q < 8; ++q)
            *(float4*)&Bt[sr_ + 32 * q][sc * 4] = st[q];
        __syncthreads();   // Bt tile ready

        // 8 rows x 4 cols fp64 FMA; dims strictly ascending (bit-exact)
#pragma unroll
        for (int dd4 = 0; dd4 < 8; ++dd4) {
            float4 af[8];
#pragma unroll
            for (int rr = 0; rr < 8; ++rr)      // wave-uniform -> LDS broadcast
                af[rr] = *(const float4*)&Bt[r0 + rg * 8 + rr][dd4 * 4];
            float4 bf[4];
#pragma unroll
            for (int k = 0; k < 4; ++k)
                bf[k] = *(const float4*)&Bt[cbase + 64 * k][dd4 * 4];

#pragma unroll
            for (int e = 0; e < 4; ++e) {
                float ae[8], be[4];
#pragma unroll
                for (int rr = 0; rr < 8; ++rr)
                    ae[rr] = (e == 0) ? af[rr].x : (e == 1) ? af[rr].y
                           : (e == 2) ? af[rr].z : af[rr].w;
#pragma unroll
                for (int k = 0; k < 4; ++k)
                    be[k] = (e == 0) ? bf[k].x : (e == 1) ? bf[k].y
                          : (e == 2) ? bf[k].z : bf[k].w;
                double ad[8], bd[4];
#pragma unroll
                for (int rr = 0; rr < 8; ++rr) ad[rr] = (double)ae[rr];
#pragma unroll
                for (int k = 0; k < 4; ++k)    bd[k]  = (double)be[k];
#pragma unroll
                for (int rr = 0; rr < 8; ++rr)
#pragma unroll
                    for (int k = 0; k < 4; ++k)
                        acc[rr][k] = fma(ad[rr], bd[k], acc[rr][k]);
            }
        }
    }

    // sigmoid (reference fp32 chain) -> S
#pragma unroll
    for (int rr = 0; rr < 8; ++rr)
#pragma unroll
        for (int k = 0; k < 4; ++k) {
            float s32 = (float)acc[rr][k];
            S[rg * 8 + rr][cbase + 64 * k] = 1.0f / (1.0f + expf(-s32));
        }
    __syncthreads();

    // top-16 per row (desc value, ties -> lowest index)
    if (t < RT) {
        float tv[TOPK]; int ti[TOPK];
#pragma unroll
        for (int q = 0; q < TOPK; ++q) { tv[q] = -INFINITY; ti[q] = 0; }
        for (int cc = 0; cc < BINSZ; ++cc) {
            float v = S[t][cc];
            if (v > tv[TOPK - 1]) {
                tv[TOPK - 1] = v; ti[TOPK - 1] = cc;
#pragma unroll
                for (int q = TOPK - 1; q > 0; --q) {
                    if (tv[q] > tv[q - 1]) {
                        float fv = tv[q]; tv[q] = tv[q - 1]; tv[q - 1] = fv;
                        int   fi = ti[q]; ti[q] = ti[q - 1]; ti[q - 1] = fi;
                    }
                }
            }
        }
#pragma unroll
        for (int q = 0; q < TOPK; ++q) {
            tvs[t][q] = tv[q];
            tds[t][q] = idx[ti[q]];
        }
    }
    // barrier drains vmcnt(0): all nt zero stores committed before scatter
    __syncthreads();

    // scatter 512 values into the zeroed rows
#pragma unroll
    for (int p = t; p < RT * TOPK; p += 256) {
        int r = p >> 4, q = p & 15;
        float* orow = out + ((size_t)b * NN + idx[r0 + r]) * NN;
        orow[tds[r][q]] = tvs[r][q];
    }
}

// ---------------------------------------------------------------------------
extern "C" void kernel_launch(void* const* d_in, const int* in_sizes, int n_in,
                              void* d_out, int out_size, void* d_ws, size_t ws_size,
                              hipStream_t stream) {
    const float* x  = (const float*)d_in[0];
    const float* cb = (const float*)d_in[1];
    float* out      = (float*)d_out;

    int* bin_idx = (int*)d_ws;           // NPTS ints
    int* order   = bin_idx + NPTS;       // NPTS ints

    k_bins<<<NPTS / 64, 64, 0, stream>>>(x, cb, bin_idx);
    k_sort<<<BB, 256, 0, stream>>>(bin_idx, order);
    k_sim<<<BB * NBINS * 8, 256, 0, stream>>>(x, order, out);
}

// Round 6
// 661.733 us; speedup vs baseline: 1.0525x; 1.0525x over previous
//
#include <hip/hip_runtime.h>
#include <math.h>

// Problem constants (match reference):
#define BB    2
#define NN    8192
#define DD    256
#define NBINS 32
#define BINSZ 256
#define NPROJ 16     // n_bins // 2
#define TOPK  16
#define NPTS  (BB * NN)   // 16384

typedef float vf4 __attribute__((ext_vector_type(4)));  // native vec for nt-store

// ---------------------------------------------------------------------------
// K1: bin assignment (numerics unchanged since R1 — absmax 0.0, don't touch).
// ---------------------------------------------------------------------------
__global__ __launch_bounds__(64) void k_bins(const float* __restrict__ x,
                                             const float* __restrict__ cb,
                                             int* __restrict__ bin_idx) {
    __shared__ double cbd[DD][NPROJ];   // 32 KB
    const int t = threadIdx.x;          // 0..63
    for (int q = t; q < DD * 4; q += 64) {
        int d = q >> 2, j4 = q & 3;
        float4 v = *(const float4*)(cb + d * 32 + j4 * 4);
        cbd[d][j4 * 4 + 0] = (double)v.x;
        cbd[d][j4 * 4 + 1] = (double)v.y;
        cbd[d][j4 * 4 + 2] = (double)v.z;
        cbd[d][j4 * 4 + 3] = (double)v.w;
    }
    __syncthreads();

    const int p = blockIdx.x * 64 + t;            // 0..16383 (flat over B,N)
    const float* xr = x + (size_t)p * DD;

    double a[NPROJ];
#pragma unroll
    for (int j = 0; j < NPROJ; ++j) a[j] = 0.0;

    for (int d0 = 0; d0 < DD; d0 += 4) {
        float4 xv = *(const float4*)(xr + d0);
        float xs[4] = {xv.x, xv.y, xv.z, xv.w};
#pragma unroll
        for (int dd = 0; dd < 4; ++dd) {
            double xd = (double)xs[dd];
#pragma unroll
            for (int j = 0; j < NPROJ; ++j)
                a[j] = fma(cbd[d0 + dd][j], xd, a[j]);
        }
    }

    float bv = -INFINITY; int bj = 0;
#pragma unroll
    for (int j = 0; j < NPROJ; ++j) {
        float m = (float)a[j];
        if (m > bv) { bv = m; bj = j; }
    }
#pragma unroll
    for (int j = 0; j < NPROJ; ++j) {
        float m = -(float)a[j];
        if (m > bv) { bv = m; bj = j + NPROJ; }
    }
    bin_idx[p] = bj;
}

// ---------------------------------------------------------------------------
// K2: stable counting sort (unchanged — ~5 us).
// ---------------------------------------------------------------------------
__global__ __launch_bounds__(256) void k_sort(const int* __restrict__ bin_idx,
                                              int* __restrict__ order) {
    __shared__ int c[NBINS][256];   // 32 KB
    __shared__ int base[NBINS];
    const int t = threadIdx.x;
    const int b = blockIdx.x;
    const int* bi = bin_idx + b * NN;

    for (int j = 0; j < NBINS; ++j) c[j][t] = 0;
    __syncthreads();

    const int i0 = t * 32;
    for (int i = 0; i < 32; ++i) c[bi[i0 + i]][t]++;
    __syncthreads();

    if (t < NBINS) {
        int s = 0;
        for (int q = 0; q < 256; ++q) s += c[t][q];
        base[t] = s;
    }
    __syncthreads();
    if (t == 0) {
        int run = 0;
        for (int j = 0; j < NBINS; ++j) { int tmp = base[j]; base[j] = run; run += tmp; }
    }
    __syncthreads();
    if (t < NBINS) {
        int run = base[t];
        for (int q = 0; q < 256; ++q) { int tmp = c[t][q]; c[t][q] = run; run += tmp; }
    }
    __syncthreads();

    int* ob = order + b * NN;
    for (int i = 0; i < 32; ++i) {
        int gi = i0 + i;
        int bb = bi[gi];
        int pos = c[bb][t]++;
        ob[pos] = gi;
    }
}

// ---------------------------------------------------------------------------
// K3 v4 — BARRIER-FREE K-loop:
//  - A-tile (32 rows x 256 dims, fp32) staged ONCE into LDS; ONE barrier,
//    issued before any store -> no vmcnt(0) drain ever lands mid-loop.
//  - 16 iters x 16-dim chunks: per iter, B-col loads issued FIRST, then
//    2 rows of nt zero stores, then FMA. Load-waits (vmcnt(N), N = younger
//    stores) drain only stores >=1 iter old -> store retire overlaps compute;
//    steady state = HBM store-rate floor.
//  - thread tile 8 rows x 4 cols; A reads wave-uniform LDS broadcasts.
//  - fp64 FMA, dims strictly ascending (it->dd4->elem) == reference: absmax 0.
// grid = 512 blocks -> 2 blocks/CU; LDS ~71 KB; VGPR ~180 (no spill at 2/CU).
// ---------------------------------------------------------------------------
#define RT 32
__global__ __launch_bounds__(256, 2) void k_sim(const float* __restrict__ x,
                                                const int* __restrict__ order,
                                                float* __restrict__ out) {
    __shared__ int   idx[BINSZ];            // 1 KB
    __shared__ float As[RT][260];           // 33.3 KB (260: 16B-align, odd/4 banks)
    __shared__ float S[RT][BINSZ + 1];      // ~32.9 KB
    __shared__ float tvs[RT][TOPK];         // 2 KB
    __shared__ int   tds[RT][TOPK];         // 2 KB

    const int t   = threadIdx.x;
    const int bid = blockIdx.x;              // 0..511
    const int b   = bid >> 8;
    const int bin = (bid >> 3) & 31;
    const int r0  = (bid & 7) * RT;

    idx[t] = order[b * NN + bin * BINSZ + t];
    __syncthreads();

    const float* xb = x + (size_t)b * NN * DD;

    // ---- stage A rows r0..r0+31 (all 256 dims) into LDS, coalesced ----
    {
        const int ar = t >> 3;               // 0..31
        const int ac = t & 7;                // 0..7
        const float* ag = xb + (size_t)idx[r0 + ar] * DD;
#pragma unroll
        for (int q = 0; q < 8; ++q) {
            // slot ac+8q: for fixed q, lanes cover 8 rows x contiguous 128 B
            float4 v = *(const float4*)(ag + (ac + 8 * q) * 4);
            *(float4*)&As[ar][(ac + 8 * q) * 4] = v;
        }
    }

    // compute assignment: rows rg*8..rg*8+7 (block-local), cols (t&63)+64k
    const int rg    = t >> 6;                // wave id -> A reads wave-uniform
    const int cbase = t & 63;
    const float* colp[4];
#pragma unroll
    for (int k = 0; k < 4; ++k)
        colp[k] = xb + (size_t)idx[cbase + 64 * k] * DD;

    double acc[8][4];
#pragma unroll
    for (int r = 0; r < 8; ++r)
#pragma unroll
        for (int k = 0; k < 4; ++k) acc[r][k] = 0.0;

    const vf4 z4 = (vf4)0.0f;

    __syncthreads();   // A-tile ready. The ONLY barrier before the epilogue.

#pragma unroll 1
    for (int it = 0; it < 16; ++it) {
        const int k0 = it * 16;

        // ---- B-col loads FIRST (older than this iter's stores) ----
        float4 bv[4][4];
#pragma unroll
        for (int k = 0; k < 4; ++k)
#pragma unroll
            for (int q = 0; q < 4; ++q)
                bv[k][q] = *(const float4*)(colp[k] + k0 + q * 4);

        // ---- zero 2 of this block's 32 output rows (fire-and-forget) ----
        {
            const int zr = it * 2;
#pragma unroll
            for (int rr = 0; rr < 2; ++rr) {
                vf4* orow = (vf4*)(out + ((size_t)b * NN + idx[r0 + zr + rr]) * NN);
#pragma unroll
                for (int j = 0; j < 8; ++j)
                    __builtin_nontemporal_store(z4, orow + j * 256 + t);
            }
        }

        // ---- FMA: 8 rows x 4 cols, dims strictly ascending ----
#pragma unroll
        for (int dd4 = 0; dd4 < 4; ++dd4) {
            float4 af[8];
#pragma unroll
            for (int rr = 0; rr < 8; ++rr)   // wave-uniform -> LDS broadcast
                af[rr] = *(const float4*)&As[rg * 8 + rr][k0 + dd4 * 4];
            const float4 b0 = bv[0][dd4], b1 = bv[1][dd4],
                         b2 = bv[2][dd4], b3 = bv[3][dd4];
#pragma unroll
            for (int e = 0; e < 4; ++e) {
                const double be0 = (double)((e == 0) ? b0.x : (e == 1) ? b0.y : (e == 2) ? b0.z : b0.w);
                const double be1 = (double)((e == 0) ? b1.x : (e == 1) ? b1.y : (e == 2) ? b1.z : b1.w);
                const double be2 = (double)((e == 0) ? b2.x : (e == 1) ? b2.y : (e == 2) ? b2.z : b2.w);
                const double be3 = (double)((e == 0) ? b3.x : (e == 1) ? b3.y : (e == 2) ? b3.z : b3.w);
#pragma unroll
                for (int rr = 0; rr < 8; ++rr) {
                    const float ae = (e == 0) ? af[rr].x : (e == 1) ? af[rr].y
                                   : (e == 2) ? af[rr].z : af[rr].w;
                    const double ad = (double)ae;
                    acc[rr][0] = fma(ad, be0, acc[rr][0]);
                    acc[rr][1] = fma(ad, be1, acc[rr][1]);
                    acc[rr][2] = fma(ad, be2, acc[rr][2]);
                    acc[rr][3] = fma(ad, be3, acc[rr][3]);
                }
            }
        }
    }

    // ---- sigmoid (reference fp32 chain) -> S ----
#pragma unroll
    for (int rr = 0; rr < 8; ++rr)
#pragma unroll
        for (int k = 0; k < 4; ++k) {
            float s32 = (float)acc[rr][k];
            S[rg * 8 + rr][cbase + 64 * k] = 1.0f / (1.0f + expf(-s32));
        }
    __syncthreads();   // also begins draining the zero stores (vmcnt(0))

    // ---- top-16 per row (desc value, ties -> lowest index) ----
    if (t < RT) {
        float tv[TOPK]; int ti[TOPK];
#pragma unroll
        for (int q = 0; q < TOPK; ++q) { tv[q] = -INFINITY; ti[q] = 0; }
        for (int cc = 0; cc < BINSZ; ++cc) {
            float v = S[t][cc];
            if (v > tv[TOPK - 1]) {
                tv[TOPK - 1] = v; ti[TOPK - 1] = cc;
#pragma unroll
                for (int q = TOPK - 1; q > 0; --q) {
                    if (tv[q] > tv[q - 1]) {
                        float fv = tv[q]; tv[q] = tv[q - 1]; tv[q - 1] = fv;
                        int   fi = ti[q]; ti[q] = ti[q - 1]; ti[q - 1] = fi;
                    }
                }
            }
        }
#pragma unroll
        for (int q = 0; q < TOPK; ++q) {
            tvs[t][q] = tv[q];
            tds[t][q] = idx[ti[q]];
        }
    }
    __syncthreads();   // tvs/tds visible; all zero stores fully drained

    // ---- scatter 512 values into the zeroed rows ----
#pragma unroll
    for (int p = t; p < RT * TOPK; p += 256) {
        int r = p >> 4, q = p & 15;
        float* orow = out + ((size_t)b * NN + idx[r0 + r]) * NN;
        orow[tds[r][q]] = tvs[r][q];
    }
}

// ---------------------------------------------------------------------------
extern "C" void kernel_launch(void* const* d_in, const int* in_sizes, int n_in,
                              void* d_out, int out_size, void* d_ws, size_t ws_size,
                              hipStream_t stream) {
    const float* x  = (const float*)d_in[0];
    const float* cb = (const float*)d_in[1];
    float* out      = (float*)d_out;

    int* bin_idx = (int*)d_ws;           // NPTS ints
    int* order   = bin_idx + NPTS;       // NPTS ints

    k_bins<<<NPTS / 64, 64, 0, stream>>>(x, cb, bin_idx);
    k_sort<<<BB, 256, 0, stream>>>(bin_idx, order);
    k_sim<<<BB * NBINS * 8, 256, 0, stream>>>(x, order, out);
}